// Round 1
// baseline (594.745 us; speedup 1.0000x reference)
//
#include <hip/hip_runtime.h>
#include <stdint.h>

#define BATCH 16
#define NROW 25200
#define NCLS 80
#define ROWF 85
#define MAXDET 300
#define MAXNMS 30000u
#define NBIN 3072
#define BASEBITS 0x3EC00000u
#define CAP 32768u
#define TILE_ROWS 80
#define TILES_PER_B 315
#define BATCH_FLOATS 2142000   // 25200*85
#define TILE_FLOATS 6800       // 80*85

// ---------------- K1: per-batch histogram of candidate score bit-bins ----------------
__global__ __launch_bounds__(256) void k_hist(const float* __restrict__ pred,
                                              unsigned* __restrict__ hist) {
    __shared__ __align__(16) float rows[TILE_FLOATS];
    __shared__ unsigned shist[NBIN];
    int bx = blockIdx.x;
    int b = bx / TILES_PER_B, tile = bx - b * TILES_PER_B;
    int t = threadIdx.x;
    for (int i = t; i < NBIN; i += 256) shist[i] = 0u;
    const float4* src = (const float4*)(pred + (size_t)b * BATCH_FLOATS + (size_t)tile * TILE_FLOATS);
    float4* dst = (float4*)rows;
    for (int i = t; i < TILE_FLOATS / 4; i += 256) dst[i] = src[i];
    __syncthreads();
    for (int p = t; p < TILE_ROWS * NCLS; p += 256) {
        int r = p / NCLS, c = p - r * NCLS;
        float obj = rows[r * ROWF + 4];
        float cv  = rows[r * ROWF + 5 + c];
        float s = __fmul_rn(cv, obj);   // exact numpy op order: cls * obj
        if (obj > 0.4f && s > 0.4f) {
            unsigned bits = __float_as_uint(s);
            unsigned bin = (bits - BASEBITS) >> 12;
            if (bin > (unsigned)(NBIN - 1)) bin = NBIN - 1;
            atomicAdd(&shist[bin], 1u);
        }
    }
    __syncthreads();
    unsigned* gh = hist + (size_t)b * NBIN;
    for (int i = t; i < NBIN; i += 256) {
        unsigned v = shist[i];
        if (v) atomicAdd(&gh[i], v);
    }
}

// ---------------- K2: suffix-scan histogram -> cutoff bin, need, scatter offsets -------
__global__ __launch_bounds__(256) void k_scan(const unsigned* __restrict__ hist,
                                              unsigned* __restrict__ suf,
                                              int* __restrict__ meta) {
    __shared__ unsigned sh[NBIN];
    __shared__ unsigned sS[NBIN];
    __shared__ unsigned cs[256];
    int b = blockIdx.x, t = threadIdx.x;
    const unsigned* gh = hist + (size_t)b * NBIN;
    for (int i = t; i < NBIN; i += 256) sh[i] = gh[i];
    __syncthreads();
    const int CHUNK = NBIN / 256;  // 12
    int base = t * CHUNK;
    unsigned tot = 0;
    for (int i = 0; i < CHUNK; ++i) tot += sh[base + i];
    cs[t] = tot;
    __syncthreads();
    for (int off = 1; off < 256; off <<= 1) {
        unsigned v = (t + off < 256) ? cs[t + off] : 0u;
        __syncthreads();
        cs[t] += v;
        __syncthreads();
    }
    unsigned after = (t + 1 < 256) ? cs[t + 1] : 0u;  // suffix of later chunks
    for (int i = CHUNK - 1; i >= 0; --i) {
        after += sh[base + i];
        sS[base + i] = after;   // inclusive suffix S(v)
    }
    __syncthreads();
    unsigned* gs = suf + (size_t)b * (NBIN + 1);
    for (int i = t; i < NBIN; i += 256) gs[i] = sS[i];
    if (t == 0) gs[NBIN] = 0u;
    for (int i = 0; i < CHUNK; ++i) {
        int v = base + i;
        unsigned Sv = sS[v];
        unsigned Sn = (v + 1 < NBIN) ? sS[v + 1] : 0u;
        if (Sv >= MAXNMS && Sn < MAXNMS) {   // unique crossing bin
            meta[b * 4 + 0] = v;
            meta[b * 4 + 1] = (int)(MAXNMS - Sn);  // need from cutbin
            meta[b * 4 + 2] = (int)Sv;             // total scattered
        }
    }
    if (t == 0 && sS[0] < MAXNMS) {   // fewer than 30000 candidates total
        meta[b * 4 + 0] = 0;
        meta[b * 4 + 1] = 0x7FFFFFFF;
        meta[b * 4 + 2] = (int)sS[0];
    }
}

// ---------------- K3: counting-scatter of top-30000 keys (bin-major order) ------------
__global__ __launch_bounds__(256) void k_scatter(const float* __restrict__ pred,
                                                 const unsigned* __restrict__ suf,
                                                 const int* __restrict__ meta,
                                                 unsigned* __restrict__ cursor,
                                                 unsigned long long* __restrict__ keys) {
    __shared__ __align__(16) float rows[TILE_FLOATS];
    int bx = blockIdx.x;
    int b = bx / TILES_PER_B, tile = bx - b * TILES_PER_B;
    int t = threadIdx.x;
    int cutbin = meta[b * 4 + 0];
    const float4* src = (const float4*)(pred + (size_t)b * BATCH_FLOATS + (size_t)tile * TILE_FLOATS);
    float4* dst = (float4*)rows;
    for (int i = t; i < TILE_FLOATS / 4; i += 256) dst[i] = src[i];
    __syncthreads();
    const unsigned* gs = suf + (size_t)b * (NBIN + 1);
    unsigned* cur = cursor + (size_t)b * NBIN;
    unsigned long long* kb = keys + (size_t)b * CAP;
    for (int p = t; p < TILE_ROWS * NCLS; p += 256) {
        int r = p / NCLS, c = p - r * NCLS;
        float obj = rows[r * ROWF + 4];
        float cv  = rows[r * ROWF + 5 + c];
        float s = __fmul_rn(cv, obj);
        if (obj > 0.4f && s > 0.4f) {
            unsigned bits = __float_as_uint(s);
            unsigned bin = (bits - BASEBITS) >> 12;
            if (bin > (unsigned)(NBIN - 1)) bin = NBIN - 1;
            if ((int)bin >= cutbin) {
                unsigned pos = gs[bin + 1] + atomicAdd(&cur[bin], 1u);
                if (pos < CAP) {
                    unsigned flat = (unsigned)((tile * TILE_ROWS + r) * NCLS + c);
                    // key: score bits desc, then flat index asc (via complement)
                    kb[pos] = ((unsigned long long)bits << 32) |
                              (unsigned long long)(0xFFFFFFFFu - flat);
                }
            }
        }
    }
}

// ---------------- K4: greedy NMS, one wave per batch ---------------------------------
__global__ __launch_bounds__(64) void k_nms(const float* __restrict__ pred,
                                            const unsigned* __restrict__ suf,
                                            const int* __restrict__ meta,
                                            const unsigned long long* __restrict__ keys,
                                            float* __restrict__ out) {
    __shared__ unsigned long long skeys[2048];
    __shared__ float kept[MAXDET][5];     // ox1,oy1,ox2,oy2,area (stride 5: bank-safe)
    __shared__ float cand[64][13];        // x1,y1,x2,y2,ox1,oy1,ox2,oy2,area,score,cls (+pad)
    int b = blockIdx.x;
    int lane = threadIdx.x;
    int cutbin = meta[b * 4 + 0];
    unsigned need = (unsigned)meta[b * 4 + 1];
    unsigned total = (unsigned)meta[b * 4 + 2];
    if (total > CAP) total = CAP;
    const unsigned* gs = suf + (size_t)b * (NBIN + 1);
    const unsigned long long* kb = keys + (size_t)b * CAP;
    const float* pb = pred + (size_t)b * BATCH_FLOATS;
    float* ob = out + (size_t)b * MAXDET * 6;
    unsigned p = 0;
    int nk = 0;
    while (p < total && nk < MAXDET) {
        unsigned long long k0 = kb[p];
        unsigned bits0 = (unsigned)(k0 >> 32);
        unsigned v = (bits0 - BASEBITS) >> 12;
        if (v > (unsigned)(NBIN - 1)) v = NBIN - 1;
        unsigned segEnd = gs[v];
        if (segEnd > total) segEnd = total;
        unsigned m = segEnd - p;
        if (m > 2048u) m = 2048u;  // defensive cap; bins hold ~<150 for this data
        for (unsigned i = lane; i < m; i += 64) skeys[i] = kb[p + i];
        __syncthreads();
        // odd-even transposition sort, descending (value desc, index asc)
        for (unsigned pass = 0; pass < m; ++pass) {
            for (unsigned i = (pass & 1u) + 2u * (unsigned)lane; i + 1 < m; i += 128u) {
                unsigned long long a = skeys[i], bb = skeys[i + 1];
                if (bb > a) { skeys[i] = bb; skeys[i + 1] = a; }
            }
            __syncthreads();
        }
        unsigned proc = m;
        if ((int)v == cutbin && need < proc) proc = need;  // exact top-30000 boundary
        for (unsigned c0 = 0; c0 < proc && nk < MAXDET; c0 += 64) {
            unsigned mm = proc - c0;
            if (mm > 64u) mm = 64u;
            if ((unsigned)lane < mm) {
                unsigned long long kk = skeys[c0 + lane];
                unsigned bits = (unsigned)(kk >> 32);
                unsigned flat = 0xFFFFFFFFu - (unsigned)kk;
                unsigned bi = flat / (unsigned)NCLS;
                unsigned cc = flat - bi * (unsigned)NCLS;
                const float* rowp = pb + (size_t)bi * ROWF;
                float cx = rowp[0], cy = rowp[1], w = rowp[2], h = rowp[3];
                float hw = __fmul_rn(0.5f, w), hh = __fmul_rn(0.5f, h);
                float x1 = __fsub_rn(cx, hw), y1 = __fsub_rn(cy, hh);
                float x2 = __fadd_rn(cx, hw), y2 = __fadd_rn(cy, hh);
                float off = (float)cc * 4096.0f;  // exact
                float ox1 = __fadd_rn(x1, off), oy1 = __fadd_rn(y1, off);
                float ox2 = __fadd_rn(x2, off), oy2 = __fadd_rn(y2, off);
                float area = __fmul_rn(__fsub_rn(ox2, ox1), __fsub_rn(oy2, oy1));
                cand[lane][0] = x1;  cand[lane][1] = y1;
                cand[lane][2] = x2;  cand[lane][3] = y2;
                cand[lane][4] = ox1; cand[lane][5] = oy1;
                cand[lane][6] = ox2; cand[lane][7] = oy2;
                cand[lane][8] = area;
                cand[lane][9] = __uint_as_float(bits);
                cand[lane][10] = (float)cc;
            }
            __syncthreads();
            for (unsigned j = 0; j < mm && nk < MAXDET; ++j) {
                float ox1 = cand[j][4], oy1 = cand[j][5];
                float ox2 = cand[j][6], oy2 = cand[j][7];
                float ar = cand[j][8];
                bool sup = false;
                for (int k = lane; k < nk; k += 64) {
                    float kx1 = kept[k][0], ky1 = kept[k][1];
                    float kx2 = kept[k][2], ky2 = kept[k][3], ka = kept[k][4];
                    float ltx = fmaxf(kx1, ox1), lty = fmaxf(ky1, oy1);
                    float rbx = fminf(kx2, ox2), rby = fminf(ky2, oy2);
                    float wx = fmaxf(__fsub_rn(rbx, ltx), 0.0f);
                    float wy = fmaxf(__fsub_rn(rby, lty), 0.0f);
                    float inter = __fmul_rn(wx, wy);
                    // reference order: areas[kept] + areas[cand] - inter + 1e-9
                    float den = __fadd_rn(__fsub_rn(__fadd_rn(ka, ar), inter), 1e-9f);
                    float iou = __fdiv_rn(inter, den);
                    if (iou > 0.5f) sup = true;
                }
                bool any = __any(sup);
                if (!any) {
                    if (lane < 5) kept[nk][lane] = cand[j][4 + lane];
                    if (lane < 6) {
                        float vout = (lane < 4) ? cand[j][lane]
                                   : (lane == 4 ? cand[j][9] : cand[j][10]);
                        ob[nk * 6 + lane] = vout;
                    }
                    nk++;
                }
                __syncthreads();
            }
            __syncthreads();
        }
        p = segEnd;
        __syncthreads();
    }
}

// ---------------- launch --------------------------------------------------------------
extern "C" void kernel_launch(void* const* d_in, const int* in_sizes, int n_in,
                              void* d_out, int out_size, void* d_ws, size_t ws_size,
                              hipStream_t stream) {
    const float* pred = (const float*)d_in[0];
    float* outp = (float*)d_out;
    char* ws = (char*)d_ws;

    // workspace layout (bytes)
    const size_t OFF_KEYS   = 0;
    const size_t SZ_KEYS    = (size_t)BATCH * CAP * 8;            // 4,194,304
    const size_t OFF_HIST   = OFF_KEYS + SZ_KEYS;
    const size_t SZ_HIST    = (size_t)BATCH * NBIN * 4;           // 196,608
    const size_t OFF_CUR    = OFF_HIST + SZ_HIST;
    const size_t SZ_CUR     = (size_t)BATCH * NBIN * 4;           // 196,608
    const size_t OFF_META   = OFF_CUR + SZ_CUR;
    const size_t SZ_META    = (size_t)BATCH * 4 * 4;              // 256
    const size_t OFF_SUF    = OFF_META + SZ_META;

    unsigned long long* keys = (unsigned long long*)(ws + OFF_KEYS);
    unsigned* hist   = (unsigned*)(ws + OFF_HIST);
    unsigned* cursor = (unsigned*)(ws + OFF_CUR);
    int* meta        = (int*)(ws + OFF_META);
    unsigned* suf    = (unsigned*)(ws + OFF_SUF);

    // zero hist + cursor + meta (one contiguous range), and output
    hipMemsetAsync(ws + OFF_HIST, 0, SZ_HIST + SZ_CUR + SZ_META, stream);
    hipMemsetAsync(d_out, 0, (size_t)out_size * sizeof(float), stream);

    k_hist<<<dim3(BATCH * TILES_PER_B), dim3(256), 0, stream>>>(pred, hist);
    k_scan<<<dim3(BATCH), dim3(256), 0, stream>>>(hist, suf, meta);
    k_scatter<<<dim3(BATCH * TILES_PER_B), dim3(256), 0, stream>>>(pred, suf, meta, cursor, keys);
    k_nms<<<dim3(BATCH), dim3(64), 0, stream>>>(pred, suf, meta, keys, outp);
}

// Round 2
// 472.598 us; speedup vs baseline: 1.2585x; 1.2585x over previous
//
#include <hip/hip_runtime.h>
#include <stdint.h>

#define BATCH 16
#define NROW 25200
#define NCLS 80
#define ROWF 85
#define MAXDET 300
#define MAXNMS 30000u
#define NBIN 3072
#define BASEBITS 0x3EC00000u
#define CAP 32768u
#define TILE_ROWS 80
#define TILES_PER_B 315
#define BATCH_FLOATS 2142000   // 25200*85
#define TILE_FLOATS 6800       // 80*85

#define GATHER_MIN 768u
#define SORTCAP 1024
#define CH_MAX 512

// ---------------- K1: per-batch histogram of candidate score bit-bins ----------------
__global__ __launch_bounds__(256) void k_hist(const float* __restrict__ pred,
                                              unsigned* __restrict__ hist) {
    __shared__ __align__(16) float rows[TILE_FLOATS];
    __shared__ unsigned shist[NBIN];
    int bx = blockIdx.x;
    int b = bx / TILES_PER_B, tile = bx - b * TILES_PER_B;
    int t = threadIdx.x;
    for (int i = t; i < NBIN; i += 256) shist[i] = 0u;
    const float4* src = (const float4*)(pred + (size_t)b * BATCH_FLOATS + (size_t)tile * TILE_FLOATS);
    float4* dst = (float4*)rows;
    for (int i = t; i < TILE_FLOATS / 4; i += 256) dst[i] = src[i];
    __syncthreads();
    for (int p = t; p < TILE_ROWS * NCLS; p += 256) {
        int r = p / NCLS, c = p - r * NCLS;
        float obj = rows[r * ROWF + 4];
        float cv  = rows[r * ROWF + 5 + c];
        float s = __fmul_rn(cv, obj);   // exact numpy op order: cls * obj
        if (obj > 0.4f && s > 0.4f) {
            unsigned bits = __float_as_uint(s);
            unsigned bin = (bits - BASEBITS) >> 12;
            if (bin > (unsigned)(NBIN - 1)) bin = NBIN - 1;
            atomicAdd(&shist[bin], 1u);
        }
    }
    __syncthreads();
    unsigned* gh = hist + (size_t)b * NBIN;
    for (int i = t; i < NBIN; i += 256) {
        unsigned v = shist[i];
        if (v) atomicAdd(&gh[i], v);
    }
}

// ---------------- K2: suffix-scan histogram -> cutoff bin, need, scatter offsets -------
__global__ __launch_bounds__(256) void k_scan(const unsigned* __restrict__ hist,
                                              unsigned* __restrict__ suf,
                                              int* __restrict__ meta) {
    __shared__ unsigned sh[NBIN];
    __shared__ unsigned sS[NBIN];
    __shared__ unsigned cs[256];
    int b = blockIdx.x, t = threadIdx.x;
    const unsigned* gh = hist + (size_t)b * NBIN;
    for (int i = t; i < NBIN; i += 256) sh[i] = gh[i];
    __syncthreads();
    const int CHUNK = NBIN / 256;  // 12
    int base = t * CHUNK;
    unsigned tot = 0;
    for (int i = 0; i < CHUNK; ++i) tot += sh[base + i];
    cs[t] = tot;
    __syncthreads();
    for (int off = 1; off < 256; off <<= 1) {
        unsigned v = (t + off < 256) ? cs[t + off] : 0u;
        __syncthreads();
        cs[t] += v;
        __syncthreads();
    }
    unsigned after = (t + 1 < 256) ? cs[t + 1] : 0u;  // suffix of later chunks
    for (int i = CHUNK - 1; i >= 0; --i) {
        after += sh[base + i];
        sS[base + i] = after;   // inclusive suffix S(v)
    }
    __syncthreads();
    unsigned* gs = suf + (size_t)b * (NBIN + 1);
    for (int i = t; i < NBIN; i += 256) gs[i] = sS[i];
    if (t == 0) gs[NBIN] = 0u;
    for (int i = 0; i < CHUNK; ++i) {
        int v = base + i;
        unsigned Sv = sS[v];
        unsigned Sn = (v + 1 < NBIN) ? sS[v + 1] : 0u;
        if (Sv >= MAXNMS && Sn < MAXNMS) {   // unique crossing bin
            meta[b * 4 + 0] = v;
            meta[b * 4 + 1] = (int)(MAXNMS - Sn);  // need from cutbin
            meta[b * 4 + 2] = (int)Sv;             // total scattered
        }
    }
    if (t == 0 && sS[0] < MAXNMS) {   // fewer than 30000 candidates total
        meta[b * 4 + 0] = 0;
        meta[b * 4 + 1] = 0x7FFFFFFF;
        meta[b * 4 + 2] = (int)sS[0];
    }
}

// ---------------- K3: counting-scatter of top-30000 keys (bin-major order) ------------
__global__ __launch_bounds__(256) void k_scatter(const float* __restrict__ pred,
                                                 const unsigned* __restrict__ suf,
                                                 const int* __restrict__ meta,
                                                 unsigned* __restrict__ cursor,
                                                 unsigned long long* __restrict__ keys) {
    __shared__ __align__(16) float rows[TILE_FLOATS];
    int bx = blockIdx.x;
    int b = bx / TILES_PER_B, tile = bx - b * TILES_PER_B;
    int t = threadIdx.x;
    int cutbin = meta[b * 4 + 0];
    const float4* src = (const float4*)(pred + (size_t)b * BATCH_FLOATS + (size_t)tile * TILE_FLOATS);
    float4* dst = (float4*)rows;
    for (int i = t; i < TILE_FLOATS / 4; i += 256) dst[i] = src[i];
    __syncthreads();
    const unsigned* gs = suf + (size_t)b * (NBIN + 1);
    unsigned* cur = cursor + (size_t)b * NBIN;
    unsigned long long* kb = keys + (size_t)b * CAP;
    for (int p = t; p < TILE_ROWS * NCLS; p += 256) {
        int r = p / NCLS, c = p - r * NCLS;
        float obj = rows[r * ROWF + 4];
        float cv  = rows[r * ROWF + 5 + c];
        float s = __fmul_rn(cv, obj);
        if (obj > 0.4f && s > 0.4f) {
            unsigned bits = __float_as_uint(s);
            unsigned bin = (bits - BASEBITS) >> 12;
            if (bin > (unsigned)(NBIN - 1)) bin = NBIN - 1;
            if ((int)bin >= cutbin) {
                unsigned pos = gs[bin + 1] + atomicAdd(&cur[bin], 1u);
                if (pos < CAP) {
                    unsigned flat = (unsigned)((tile * TILE_ROWS + r) * NCLS + c);
                    // key: score bits desc, then flat index asc (via complement)
                    kb[pos] = ((unsigned long long)bits << 32) |
                              (unsigned long long)(0xFFFFFFFFu - flat);
                }
            }
        }
    }
}

// ---------------- K4: mask-based greedy NMS, one block (8 waves) per batch ------------
__global__ __launch_bounds__(512) void k_nms(const float* __restrict__ pred,
                                             const unsigned* __restrict__ suf,
                                             const int* __restrict__ meta,
                                             const unsigned long long* __restrict__ keys,
                                             float* __restrict__ out) {
    __shared__ unsigned long long skeys[SORTCAP];          // 8 KB
    __shared__ unsigned long long mask[CH_MAX][8];         // 32 KB
    __shared__ float cbox[CH_MAX][5];                      // 10 KB  (ox1,oy1,ox2,oy2,area)
    __shared__ float kept[MAXDET][5];                      // 6 KB
    __shared__ int klist[MAXDET];
    __shared__ unsigned long long supW[8];
    __shared__ int s_nk, s_localk;

    int b = blockIdx.x;
    int tid = threadIdx.x;
    int lane = tid & 63, wv = tid >> 6;

    int cutbin = meta[b * 4 + 0];
    unsigned need = (unsigned)meta[b * 4 + 1];
    unsigned total = (unsigned)meta[b * 4 + 2];
    if (total > CAP) total = CAP;
    const unsigned* gs = suf + (size_t)b * (NBIN + 1);
    const unsigned long long* kb = keys + (size_t)b * CAP;
    const float* pb = pred + (size_t)b * BATCH_FLOATS;
    float* ob = out + (size_t)b * MAXDET * 6;

    unsigned limit = (need == 0x7FFFFFFF) ? total : (gs[cutbin + 1] + (unsigned)need);
    if (limit > total) limit = total;

    if (tid == 0) s_nk = 0;
    __syncthreads();

    unsigned p = 0;
    while (p < limit) {
        if (s_nk >= MAXDET) break;   // uniform: post-barrier value

        // ---- choose gather extent [p, gEnd): whole bins, >= GATHER_MIN keys, <= SORTCAP ----
        // w1 = largest v with gs[v] > p (bin containing position p)
        int lo = cutbin, hi = NBIN - 1, w1 = cutbin;
        while (lo <= hi) { int mid = (lo + hi) >> 1;
            if (gs[mid] > p) { w1 = mid; lo = mid + 1; } else hi = mid - 1; }
        // w2 = largest v with gs[v] >= p + GATHER_MIN (or cutbin if none)
        lo = cutbin; hi = NBIN - 1; int w2 = cutbin;
        while (lo <= hi) { int mid = (lo + hi) >> 1;
            if (gs[mid] >= p + GATHER_MIN) { w2 = mid; lo = mid + 1; } else hi = mid - 1; }
        unsigned gEnd = gs[w2];
        if (gEnd <= p) gEnd = gs[cutbin];                 // degenerate safety
        if (gEnd - p > (unsigned)SORTCAP) {
            if (w2 < w1) gEnd = gs[w2 + 1];               // one fewer bin, still a full-bin prefix
            if (gEnd - p > (unsigned)SORTCAP) gEnd = p + SORTCAP;  // unreachable for this data
        }
        unsigned G = gEnd - p;

        // ---- gather + pad + bitonic sort (descending; key carries value desc, idx asc) ----
        int n = 1; while (n < (int)G) n <<= 1;
        for (int i = tid; i < n; i += 512) skeys[i] = (i < (int)G) ? kb[p + i] : 0ULL;
        __syncthreads();
        for (int k = 2; k <= n; k <<= 1) {
            for (int j = k >> 1; j > 0; j >>= 1) {
                for (int i = tid; i < n; i += 512) {
                    int ix = i ^ j;
                    if (ix > i) {
                        unsigned long long a = skeys[i], c = skeys[ix];
                        bool desc = ((i & k) == 0);
                        if (desc ? (a < c) : (a > c)) { skeys[i] = c; skeys[ix] = a; }
                    }
                }
                __syncthreads();
            }
        }

        unsigned consumable = limit - p; if (consumable > G) consumable = G;

        // ---- process sorted run in chunks of CH_MAX ----
        for (unsigned c0 = 0; c0 < consumable; c0 += CH_MAX) {
            int nk0 = s_nk;
            if (nk0 >= MAXDET) break;
            int CH = (int)((consumable - c0 < (unsigned)CH_MAX) ? (consumable - c0) : (unsigned)CH_MAX);

            // candidate off-boxes + areas (exact fp op order)
            for (int i = tid; i < CH; i += 512) {
                unsigned long long kk = skeys[c0 + i];
                unsigned flat = 0xFFFFFFFFu - (unsigned)kk;
                unsigned bi = flat / (unsigned)NCLS;
                unsigned cc = flat - bi * (unsigned)NCLS;
                const float* rp = pb + (size_t)bi * ROWF;
                float cx = rp[0], cy = rp[1], wd = rp[2], ht = rp[3];
                float hw = __fmul_rn(0.5f, wd), hh = __fmul_rn(0.5f, ht);
                float off = __fmul_rn((float)cc, 4096.0f);
                float x1 = __fsub_rn(cx, hw), y1 = __fsub_rn(cy, hh);
                float x2 = __fadd_rn(cx, hw), y2 = __fadd_rn(cy, hh);
                cbox[i][0] = __fadd_rn(x1, off);
                cbox[i][1] = __fadd_rn(y1, off);
                cbox[i][2] = __fadd_rn(x2, off);
                cbox[i][3] = __fadd_rn(y2, off);
                cbox[i][4] = __fmul_rn(__fsub_rn(cbox[i][2], cbox[i][0]),
                                       __fsub_rn(cbox[i][3], cbox[i][1]));
            }
            __syncthreads();

            // initial suppression vs already-kept boxes (lane i of wave wv -> bit i of word wv)
            {
                bool f = false;
                if (tid < CH) {
                    float bx1 = cbox[tid][0], by1 = cbox[tid][1];
                    float bx2 = cbox[tid][2], by2 = cbox[tid][3], ba = cbox[tid][4];
                    for (int k2 = 0; k2 < nk0; ++k2) {
                        float ax1 = kept[k2][0], ay1 = kept[k2][1];
                        float ax2 = kept[k2][2], ay2 = kept[k2][3], aa = kept[k2][4];
                        float ltx = fmaxf(ax1, bx1), lty = fmaxf(ay1, by1);
                        float rbx = fminf(ax2, bx2), rby = fminf(ay2, by2);
                        float wx = fmaxf(__fsub_rn(rbx, ltx), 0.0f);
                        float wy = fmaxf(__fsub_rn(rby, lty), 0.0f);
                        float inter = __fmul_rn(wx, wy);
                        float den = __fadd_rn(__fsub_rn(__fadd_rn(aa, ba), inter), 1e-9f);
                        if (__fdiv_rn(inter, den) > 0.5f) f = true;
                    }
                }
                unsigned long long bal = __ballot(f);
                if (lane == 0) supW[wv] = bal;
            }
            __syncthreads();

            // pairwise mask: wave wv owns 64-bit word wv; lane holds box j = wv*64+lane
            {
                int j = (wv << 6) + lane;
                bool jv = j < CH;
                float bx1 = 0, by1 = 0, bx2 = 0, by2 = 0, ba = 0;
                if (jv) { bx1 = cbox[j][0]; by1 = cbox[j][1]; bx2 = cbox[j][2]; by2 = cbox[j][3]; ba = cbox[j][4]; }
                for (int i = 0; i < CH; ++i) {
                    float ax1 = cbox[i][0], ay1 = cbox[i][1];
                    float ax2 = cbox[i][2], ay2 = cbox[i][3], aa = cbox[i][4];
                    float ltx = fmaxf(ax1, bx1), lty = fmaxf(ay1, by1);
                    float rbx = fminf(ax2, bx2), rby = fminf(ay2, by2);
                    float wx = fmaxf(__fsub_rn(rbx, ltx), 0.0f);
                    float wy = fmaxf(__fsub_rn(rby, lty), 0.0f);
                    float inter = __fmul_rn(wx, wy);
                    float den = __fadd_rn(__fsub_rn(__fadd_rn(aa, ba), inter), 1e-9f);
                    bool sp = jv && (j != i) && (__fdiv_rn(inter, den) > 0.5f);
                    unsigned long long bal = __ballot(sp);
                    if (lane == 0) mask[i][wv] = bal;
                }
            }
            __syncthreads();

            // serial greedy scan (wave 0), sup bitset in lanes 0..7, mask rows prefetched
            if (wv == 0) {
                unsigned long long supw = (lane < 8) ? supW[lane] : 0ULL;
                unsigned long long pre0 = (lane < 8 && CH > 0) ? mask[0][lane] : 0ULL;
                unsigned long long pre1 = (lane < 8 && CH > 1) ? mask[1][lane] : 0ULL;
                int nkv = nk0, lk = 0;
                for (int i = 0; i < CH && nkv < MAXDET; ++i) {
                    unsigned long long wcur = __shfl(supw, i >> 6);
                    bool sup = (wcur >> (i & 63)) & 1ULL;
                    unsigned long long row = pre0;
                    pre0 = pre1;
                    pre1 = (lane < 8 && (i + 2) < CH) ? mask[i + 2][lane] : 0ULL;
                    if (!sup) {
                        if (lane == 0) klist[lk] = i;
                        supw |= row;
                        lk++; nkv++;
                    }
                }
                if (lane == 0) { s_localk = lk; s_nk = nkv; }
            }
            __syncthreads();

            // epilogue: record kept boxes + write output rows (parallel)
            int lk = s_localk;
            for (int t2 = tid; t2 < lk; t2 += 512) {
                int i = klist[t2];
                int oidx = nk0 + t2;
                kept[oidx][0] = cbox[i][0]; kept[oidx][1] = cbox[i][1];
                kept[oidx][2] = cbox[i][2]; kept[oidx][3] = cbox[i][3];
                kept[oidx][4] = cbox[i][4];
                unsigned long long kk = skeys[c0 + i];
                unsigned bits = (unsigned)(kk >> 32);
                unsigned flat = 0xFFFFFFFFu - (unsigned)kk;
                unsigned bi = flat / (unsigned)NCLS;
                unsigned cc = flat - bi * (unsigned)NCLS;
                const float* rp = pb + (size_t)bi * ROWF;
                float cx = rp[0], cy = rp[1], wd = rp[2], ht = rp[3];
                float hw = __fmul_rn(0.5f, wd), hh = __fmul_rn(0.5f, ht);
                float* orow = ob + (size_t)oidx * 6;
                orow[0] = __fsub_rn(cx, hw);
                orow[1] = __fsub_rn(cy, hh);
                orow[2] = __fadd_rn(cx, hw);
                orow[3] = __fadd_rn(cy, hh);
                orow[4] = __uint_as_float(bits);
                orow[5] = (float)cc;
            }
            __syncthreads();
        }
        p = gEnd;
    }
}

// ---------------- launch --------------------------------------------------------------
extern "C" void kernel_launch(void* const* d_in, const int* in_sizes, int n_in,
                              void* d_out, int out_size, void* d_ws, size_t ws_size,
                              hipStream_t stream) {
    const float* pred = (const float*)d_in[0];
    float* outp = (float*)d_out;
    char* ws = (char*)d_ws;

    const size_t OFF_KEYS   = 0;
    const size_t SZ_KEYS    = (size_t)BATCH * CAP * 8;
    const size_t OFF_HIST   = OFF_KEYS + SZ_KEYS;
    const size_t SZ_HIST    = (size_t)BATCH * NBIN * 4;
    const size_t OFF_CUR    = OFF_HIST + SZ_HIST;
    const size_t SZ_CUR     = (size_t)BATCH * NBIN * 4;
    const size_t OFF_META   = OFF_CUR + SZ_CUR;
    const size_t SZ_META    = (size_t)BATCH * 4 * 4;
    const size_t OFF_SUF    = OFF_META + SZ_META;

    unsigned long long* keys = (unsigned long long*)(ws + OFF_KEYS);
    unsigned* hist   = (unsigned*)(ws + OFF_HIST);
    unsigned* cursor = (unsigned*)(ws + OFF_CUR);
    int* meta        = (int*)(ws + OFF_META);
    unsigned* suf    = (unsigned*)(ws + OFF_SUF);

    hipMemsetAsync(ws + OFF_HIST, 0, SZ_HIST + SZ_CUR + SZ_META, stream);
    hipMemsetAsync(d_out, 0, (size_t)out_size * sizeof(float), stream);

    k_hist<<<dim3(BATCH * TILES_PER_B), dim3(256), 0, stream>>>(pred, hist);
    k_scan<<<dim3(BATCH), dim3(256), 0, stream>>>(hist, suf, meta);
    k_scatter<<<dim3(BATCH * TILES_PER_B), dim3(256), 0, stream>>>(pred, suf, meta, cursor, keys);
    k_nms<<<dim3(BATCH), dim3(512), 0, stream>>>(pred, suf, meta, keys, outp);
}

// Round 3
// 418.577 us; speedup vs baseline: 1.4209x; 1.1291x over previous
//
#include <hip/hip_runtime.h>
#include <stdint.h>

#define BATCH 16
#define NROW 25200
#define NCLS 80
#define ROWF 85
#define MAXDET 300
#define MAXNMS 30000u
#define NBIN 3072
#define BASEBITS 0x3EC00000u
#define CAP 32768u
#define TILE_ROWS 80
#define BATCH_FLOATS 2142000   // 25200*85
#define TILE_FLOATS 6800       // 80*85

#define GATHER_MIN 768u
#define SORTCAP 1024
#define CH_MAX 512

// staged-path constants: pre-threshold bin 2048 ~ score 0.75 (cutoff for top-30000 is ~0.83)
#define PREBIN 2048
#define NBUCK 1024            // NBIN - PREBIN
#define BUCKCAP 256
#define RPB 400               // rows per hist block
#define SUBT 5                // sub-tiles of 80 rows
#define SBLK 63               // blocks per batch (63*400 = 25200)

// ---------------- K1: fused histogram + bucket staging (single read of pred) ---------
__global__ __launch_bounds__(256) void k_stage(const float* __restrict__ pred,
                                               unsigned* __restrict__ hist,
                                               unsigned* __restrict__ bcnt,
                                               unsigned long long* __restrict__ bucket,
                                               unsigned* __restrict__ oflow,
                                               int staged) {
    __shared__ __align__(16) float rows[TILE_FLOATS];
    __shared__ unsigned shist[NBIN];
    int bx = blockIdx.x;
    int b = bx / SBLK, blk = bx - b * SBLK;
    int t = threadIdx.x, lane = t & 63, wv = t >> 6;
    for (int i = t; i < NBIN; i += 256) shist[i] = 0u;
    const float* pbase = pred + (size_t)b * BATCH_FLOATS + (size_t)blk * RPB * ROWF;
    unsigned rowbase0 = (unsigned)(blk * RPB);
    unsigned* bc = bcnt + (size_t)b * NBUCK;
    unsigned long long* bk = bucket + (size_t)b * NBUCK * BUCKCAP;
    for (int st = 0; st < SUBT; ++st) {
        __syncthreads();
        const float4* src = (const float4*)(pbase + (size_t)st * TILE_ROWS * ROWF);
        float4* dst = (float4*)rows;
        for (int i = t; i < TILE_FLOATS / 4; i += 256) dst[i] = src[i];
        __syncthreads();
        for (int r = wv; r < TILE_ROWS; r += 4) {        // wave-per-row: uniform skip
            float obj = rows[r * ROWF + 4];
            if (!(obj > 0.4f)) continue;
            unsigned grow = rowbase0 + (unsigned)(st * TILE_ROWS + r);
            for (int half = 0; half < 2; ++half) {
                int c = lane + (half << 6);
                if (c < NCLS) {
                    float cv = rows[r * ROWF + 5 + c];
                    float s = __fmul_rn(cv, obj);        // exact numpy op order
                    if (s > 0.4f) {
                        unsigned bits = __float_as_uint(s);
                        unsigned bin = (bits - BASEBITS) >> 12;
                        if (bin > (unsigned)(NBIN - 1)) bin = NBIN - 1;
                        atomicAdd(&shist[bin], 1u);
                        if (staged && bin >= (unsigned)PREBIN) {
                            unsigned bb = bin - PREBIN;
                            unsigned pos = atomicAdd(&bc[bb], 1u);
                            if (pos < (unsigned)BUCKCAP) {
                                unsigned flat = grow * (unsigned)NCLS + (unsigned)c;
                                bk[(size_t)bb * BUCKCAP + pos] =
                                    ((unsigned long long)bits << 32) |
                                    (unsigned long long)(0xFFFFFFFFu - flat);
                            } else {
                                oflow[b] = 1u;
                            }
                        }
                    }
                }
            }
        }
    }
    __syncthreads();
    unsigned* gh = hist + (size_t)b * NBIN;
    for (int i = t; i < NBIN; i += 256) {
        unsigned v = shist[i];
        if (v) atomicAdd(&gh[i], v);
    }
}

// ---------------- K2: suffix-scan -> cutoff bin, need, validity ----------------------
__global__ __launch_bounds__(256) void k_scan(const unsigned* __restrict__ hist,
                                              unsigned* __restrict__ suf,
                                              int* __restrict__ meta,
                                              const unsigned* __restrict__ oflow,
                                              int staged) {
    __shared__ unsigned sh[NBIN];
    __shared__ unsigned sS[NBIN];
    __shared__ unsigned cs[256];
    __shared__ int s_cut, s_need, s_tot;
    int b = blockIdx.x, t = threadIdx.x;
    const unsigned* gh = hist + (size_t)b * NBIN;
    for (int i = t; i < NBIN; i += 256) sh[i] = gh[i];
    if (t == 0) { s_cut = 0; s_need = 0x7FFFFFFF; s_tot = 0; }
    __syncthreads();
    const int CHUNK = NBIN / 256;  // 12
    int base = t * CHUNK;
    unsigned tot = 0;
    for (int i = 0; i < CHUNK; ++i) tot += sh[base + i];
    cs[t] = tot;
    __syncthreads();
    for (int off = 1; off < 256; off <<= 1) {
        unsigned v = (t + off < 256) ? cs[t + off] : 0u;
        __syncthreads();
        cs[t] += v;
        __syncthreads();
    }
    unsigned after = (t + 1 < 256) ? cs[t + 1] : 0u;
    for (int i = CHUNK - 1; i >= 0; --i) {
        after += sh[base + i];
        sS[base + i] = after;
    }
    __syncthreads();
    unsigned* gs = suf + (size_t)b * (NBIN + 1);
    for (int i = t; i < NBIN; i += 256) gs[i] = sS[i];
    if (t == 0) gs[NBIN] = 0u;
    for (int i = 0; i < CHUNK; ++i) {
        int v = base + i;
        unsigned Sv = sS[v];
        unsigned Sn = (v + 1 < NBIN) ? sS[v + 1] : 0u;
        if (Sv >= MAXNMS && Sn < MAXNMS) {
            s_cut = v;
            s_need = (int)(MAXNMS - Sn);
            s_tot = (int)Sv;
        }
    }
    __syncthreads();
    if (t == 0) {
        int cut = s_cut, needv = s_need, totv = s_tot;
        if (sS[0] < MAXNMS) { cut = 0; needv = 0x7FFFFFFF; totv = (int)sS[0]; }
        int valid = (staged && cut >= PREBIN && oflow[b] == 0u) ? 1 : 0;
        meta[b * 4 + 0] = cut;
        meta[b * 4 + 1] = needv;
        meta[b * 4 + 2] = totv;
        meta[b * 4 + 3] = valid;
    }
}

// ---------------- K3 (fallback only): full re-read counting-scatter ------------------
__global__ __launch_bounds__(256) void k_scatter_fb(const float* __restrict__ pred,
                                                    const unsigned* __restrict__ suf,
                                                    const int* __restrict__ meta,
                                                    unsigned* __restrict__ cursor,
                                                    unsigned long long* __restrict__ keys) {
    int bx = blockIdx.x;
    int b = bx / SBLK, blk = bx - b * SBLK;
    if (meta[b * 4 + 3]) return;   // staged path valid for this batch -> nothing to do
    __shared__ __align__(16) float rows[TILE_FLOATS];
    int t = threadIdx.x, lane = t & 63, wv = t >> 6;
    int cutbin = meta[b * 4 + 0];
    const float* pbase = pred + (size_t)b * BATCH_FLOATS + (size_t)blk * RPB * ROWF;
    unsigned rowbase0 = (unsigned)(blk * RPB);
    const unsigned* gs = suf + (size_t)b * (NBIN + 1);
    unsigned* cur = cursor + (size_t)b * NBIN;
    unsigned long long* kb = keys + (size_t)b * CAP;
    for (int st = 0; st < SUBT; ++st) {
        __syncthreads();
        const float4* src = (const float4*)(pbase + (size_t)st * TILE_ROWS * ROWF);
        float4* dst = (float4*)rows;
        for (int i = t; i < TILE_FLOATS / 4; i += 256) dst[i] = src[i];
        __syncthreads();
        for (int r = wv; r < TILE_ROWS; r += 4) {
            float obj = rows[r * ROWF + 4];
            if (!(obj > 0.4f)) continue;
            unsigned grow = rowbase0 + (unsigned)(st * TILE_ROWS + r);
            for (int half = 0; half < 2; ++half) {
                int c = lane + (half << 6);
                if (c < NCLS) {
                    float cv = rows[r * ROWF + 5 + c];
                    float s = __fmul_rn(cv, obj);
                    if (s > 0.4f) {
                        unsigned bits = __float_as_uint(s);
                        unsigned bin = (bits - BASEBITS) >> 12;
                        if (bin > (unsigned)(NBIN - 1)) bin = NBIN - 1;
                        if ((int)bin >= cutbin) {
                            unsigned pos = gs[bin + 1] + atomicAdd(&cur[bin], 1u);
                            if (pos < CAP) {
                                unsigned flat = grow * (unsigned)NCLS + (unsigned)c;
                                kb[pos] = ((unsigned long long)bits << 32) |
                                          (unsigned long long)(0xFFFFFFFFu - flat);
                            }
                        }
                    }
                }
            }
        }
    }
}

// ---------------- K4: NMS — transposed mask, ballot-free build, any()-scan -----------
__global__ __launch_bounds__(512) void k_nms(const float* __restrict__ pred,
                                             const unsigned* __restrict__ suf,
                                             const int* __restrict__ meta,
                                             const unsigned long long* __restrict__ keys,
                                             const unsigned long long* __restrict__ bucket,
                                             float* __restrict__ out) {
    __shared__ unsigned sgs[NBUCK + 1];                    // gs[2048..3072]
    __shared__ unsigned long long skeys[SORTCAP];          // 8 KB
    __shared__ unsigned long long maskT[CH_MAX][9];        // 36.9 KB (stride 9: pad)
    __shared__ float cbox[CH_MAX][5];                      // 10 KB
    __shared__ float kept[MAXDET][5];
    __shared__ int klist[MAXDET];
    __shared__ unsigned char sup0[CH_MAX];
    __shared__ int s_nk, s_localk;

    int b = blockIdx.x;
    int tid = threadIdx.x;
    int lane = tid & 63, wv = tid >> 6;

    int cutbin = meta[b * 4 + 0];
    int needv  = meta[b * 4 + 1];
    unsigned total = (unsigned)meta[b * 4 + 2];
    int valid  = meta[b * 4 + 3];
    if (total > CAP) total = CAP;
    const unsigned* gs = suf + (size_t)b * (NBIN + 1);
    const unsigned long long* kb = keys + (size_t)b * CAP;
    const unsigned long long* bk = bucket + (size_t)b * NBUCK * BUCKCAP;
    const float* pb = pred + (size_t)b * BATCH_FLOATS;
    float* ob = out + (size_t)b * MAXDET * 6;

    if (valid) for (int i = tid; i < NBUCK + 1; i += 512) sgs[i] = gs[PREBIN + i];
    if (tid == 0) s_nk = 0;
    __syncthreads();

    unsigned limit = (needv == 0x7FFFFFFF) ? total : (gs[cutbin + 1] + (unsigned)needv);
    if (limit > total) limit = total;

#define GSV(v) (valid ? sgs[(v) - PREBIN] : gs[(v)])

    unsigned p = 0;
    while (p < limit) {
        if (s_nk >= MAXDET) break;

        // gather extent: whole bins, >= GATHER_MIN keys, <= SORTCAP
        int lo = cutbin, hi = NBIN - 1, w1 = cutbin;
        while (lo <= hi) { int mid = (lo + hi) >> 1;
            if (GSV(mid) > p) { w1 = mid; lo = mid + 1; } else hi = mid - 1; }
        lo = cutbin; hi = NBIN - 1; int w2 = cutbin;
        while (lo <= hi) { int mid = (lo + hi) >> 1;
            if (GSV(mid) >= p + GATHER_MIN) { w2 = mid; lo = mid + 1; } else hi = mid - 1; }
        unsigned gEnd = GSV(w2);
        if (gEnd <= p) gEnd = GSV(cutbin);
        if (gEnd - p > (unsigned)SORTCAP) {
            if (w2 < w1) gEnd = GSV(w2 + 1);
            if (gEnd - p > (unsigned)SORTCAP) gEnd = p + SORTCAP;
        }
        unsigned G = gEnd - p;

        // fill + pad + bitonic sort (desc by (bits, ~flat))
        int n = 1; while (n < (int)G) n <<= 1;
        for (int i = tid; i < n; i += 512) {
            unsigned long long k = 0ULL;
            if (i < (int)G) {
                unsigned idx = p + (unsigned)i;
                if (valid) {
                    int l2 = cutbin, h2 = NBIN - 1, v = cutbin;
                    while (l2 <= h2) { int mid = (l2 + h2) >> 1;
                        if (sgs[mid - PREBIN] > idx) { v = mid; l2 = mid + 1; } else h2 = mid - 1; }
                    unsigned off = idx - sgs[v + 1 - PREBIN];
                    k = bk[(size_t)(v - PREBIN) * BUCKCAP + off];
                } else {
                    k = kb[idx];
                }
            }
            skeys[i] = k;
        }
        __syncthreads();
        for (int k = 2; k <= n; k <<= 1) {
            for (int j = k >> 1; j > 0; j >>= 1) {
                for (int i = tid; i < n; i += 512) {
                    int ix = i ^ j;
                    if (ix > i) {
                        unsigned long long a = skeys[i], c = skeys[ix];
                        bool desc = ((i & k) == 0);
                        if (desc ? (a < c) : (a > c)) { skeys[i] = c; skeys[ix] = a; }
                    }
                }
                __syncthreads();
            }
        }

        unsigned consumable = limit - p; if (consumable > G) consumable = G;

        for (unsigned c0 = 0; c0 < consumable; c0 += CH_MAX) {
            int nk0 = s_nk;
            if (nk0 >= MAXDET) break;
            int CH = (int)((consumable - c0 < (unsigned)CH_MAX) ? (consumable - c0) : (unsigned)CH_MAX);

            // candidate off-box in registers + LDS; own-candidate = tid
            float bx1 = 0.f, by1 = 0.f, bx2 = 0.f, by2 = 0.f, ba = 0.f;
            bool f0 = false;
            if (tid < CH) {
                unsigned long long kk = skeys[c0 + tid];
                unsigned flat = 0xFFFFFFFFu - (unsigned)kk;
                unsigned bi = flat / (unsigned)NCLS;
                unsigned cc = flat - bi * (unsigned)NCLS;
                const float* rp = pb + (size_t)bi * ROWF;
                float cx = rp[0], cy = rp[1], wd = rp[2], ht = rp[3];
                float hw = __fmul_rn(0.5f, wd), hh = __fmul_rn(0.5f, ht);
                float off = __fmul_rn((float)cc, 4096.0f);
                float x1 = __fsub_rn(cx, hw), y1 = __fsub_rn(cy, hh);
                float x2 = __fadd_rn(cx, hw), y2 = __fadd_rn(cy, hh);
                bx1 = __fadd_rn(x1, off); by1 = __fadd_rn(y1, off);
                bx2 = __fadd_rn(x2, off); by2 = __fadd_rn(y2, off);
                ba = __fmul_rn(__fsub_rn(bx2, bx1), __fsub_rn(by2, by1));
                cbox[tid][0] = bx1; cbox[tid][1] = by1;
                cbox[tid][2] = bx2; cbox[tid][3] = by2;
                cbox[tid][4] = ba;
                // suppression vs previously-kept boxes (rare: only chunks after the first)
                for (int k2 = 0; k2 < nk0; ++k2) {
                    float ax1 = kept[k2][0], ay1 = kept[k2][1];
                    float ax2 = kept[k2][2], ay2 = kept[k2][3], aa = kept[k2][4];
                    float ltx = fmaxf(ax1, bx1), lty = fmaxf(ay1, by1);
                    float rbx = fminf(ax2, bx2), rby = fminf(ay2, by2);
                    float wx = fmaxf(__fsub_rn(rbx, ltx), 0.0f);
                    float wy = fmaxf(__fsub_rn(rby, lty), 0.0f);
                    float inter = __fmul_rn(wx, wy);
                    float den = __fadd_rn(__fsub_rn(__fadd_rn(aa, ba), inter), 1e-9f);
                    if (__fdiv_rn(inter, den) > 0.5f) f0 = true;
                }
            }
            sup0[tid] = f0 ? 1 : 0;
            __syncthreads();

            // transposed triangle mask: thread tid = column j; rows i < j, groups g<=wv
            for (int g = 0; g <= wv; ++g) {            // uniform branch per wave
                unsigned long long curw = 0ULL;
                for (int jj = 0; jj < 64; ++jj) {
                    int i2 = (g << 6) + jj;
                    float ax1 = cbox[i2][0], ay1 = cbox[i2][1];   // broadcast reads
                    float ax2 = cbox[i2][2], ay2 = cbox[i2][3], aa = cbox[i2][4];
                    float ltx = fmaxf(ax1, bx1), lty = fmaxf(ay1, by1);
                    float rbx = fminf(ax2, bx2), rby = fminf(ay2, by2);
                    float wx = fmaxf(__fsub_rn(rbx, ltx), 0.0f);
                    float wy = fmaxf(__fsub_rn(rby, lty), 0.0f);
                    float inter = __fmul_rn(wx, wy);
                    float den = __fadd_rn(__fsub_rn(__fadd_rn(aa, ba), inter), 1e-9f);
                    bool sp = (tid < CH) && (i2 < tid) && (__fdiv_rn(inter, den) > 0.5f);
                    curw |= sp ? (1ULL << jj) : 0ULL;
                }
                maskT[tid][g] = curw;
            }
            __syncthreads();

            // serial greedy scan, wave 0: sup_j = any(keptw & col_j) — no shfl
            if (wv == 0) {
                unsigned long long keptw = 0ULL;
                int nkv = nk0, lk = 0;
                bool useS = (nk0 > 0);
                unsigned long long pre0 = (lane < 8 && CH > 0) ? maskT[0][lane] : 0ULL;
                unsigned long long pre1 = (lane < 8 && CH > 1) ? maskT[1][lane] : 0ULL;
                for (int j = 0; j < CH && nkv < MAXDET; ++j) {
                    unsigned long long colw = pre0;
                    pre0 = pre1;
                    pre1 = (lane < 8 && (j + 2) < CH) ? maskT[j + 2][lane] : 0ULL;
                    bool hit = (keptw & colw) != 0ULL;
                    bool sup = __any(hit);
                    if (useS && sup0[j]) sup = true;
                    if (!sup) {
                        if (lane == (j >> 6)) keptw |= 1ULL << (j & 63);
                        if (lane == 0) klist[lk] = j;
                        lk++; nkv++;
                    }
                }
                if (lane == 0) { s_localk = lk; s_nk = nkv; }
            }
            __syncthreads();

            // epilogue: record kept + write output rows (parallel)
            int lk = s_localk;
            for (int t2 = tid; t2 < lk; t2 += 512) {
                int i = klist[t2];
                int oidx = nk0 + t2;
                kept[oidx][0] = cbox[i][0]; kept[oidx][1] = cbox[i][1];
                kept[oidx][2] = cbox[i][2]; kept[oidx][3] = cbox[i][3];
                kept[oidx][4] = cbox[i][4];
                unsigned long long kk = skeys[c0 + i];
                unsigned bits = (unsigned)(kk >> 32);
                unsigned flat = 0xFFFFFFFFu - (unsigned)kk;
                unsigned bi = flat / (unsigned)NCLS;
                unsigned cc = flat - bi * (unsigned)NCLS;
                const float* rp = pb + (size_t)bi * ROWF;
                float cx = rp[0], cy = rp[1], wd = rp[2], ht = rp[3];
                float hw = __fmul_rn(0.5f, wd), hh = __fmul_rn(0.5f, ht);
                float* orow = ob + (size_t)oidx * 6;
                orow[0] = __fsub_rn(cx, hw);
                orow[1] = __fsub_rn(cy, hh);
                orow[2] = __fadd_rn(cx, hw);
                orow[3] = __fadd_rn(cy, hh);
                orow[4] = __uint_as_float(bits);
                orow[5] = (float)cc;
            }
            __syncthreads();
        }
        p = gEnd;
    }
#undef GSV
}

// ---------------- launch --------------------------------------------------------------
extern "C" void kernel_launch(void* const* d_in, const int* in_sizes, int n_in,
                              void* d_out, int out_size, void* d_ws, size_t ws_size,
                              hipStream_t stream) {
    const float* pred = (const float*)d_in[0];
    float* outp = (float*)d_out;
    char* ws = (char*)d_ws;

    const size_t OFF_KEYS = 0;
    const size_t SZ_KEYS  = (size_t)BATCH * CAP * 8;                 // 4,194,304
    const size_t OFF_HIST = OFF_KEYS + SZ_KEYS;
    const size_t SZ_HIST  = (size_t)BATCH * NBIN * 4;                // 196,608
    const size_t OFF_CUR  = OFF_HIST + SZ_HIST;
    const size_t SZ_CUR   = (size_t)BATCH * NBIN * 4;                // 196,608
    const size_t OFF_BCNT = OFF_CUR + SZ_CUR;
    const size_t SZ_BCNT  = (size_t)BATCH * NBUCK * 4;               // 65,536
    const size_t OFF_OFLW = OFF_BCNT + SZ_BCNT;
    const size_t SZ_OFLW  = (size_t)BATCH * 4;                       // 64
    const size_t OFF_META = OFF_OFLW + SZ_OFLW;
    const size_t SZ_META  = (size_t)BATCH * 4 * 4;                   // 256
    const size_t OFF_SUF  = OFF_META + SZ_META;
    const size_t SZ_SUF   = (size_t)BATCH * (NBIN + 1) * 4;          // 196,672
    const size_t OFF_BUCK = OFF_SUF + SZ_SUF;
    const size_t SZ_BUCK  = (size_t)BATCH * NBUCK * BUCKCAP * 8;     // 33,554,432
    const size_t WS_NEEDED = OFF_BUCK + SZ_BUCK;

    int staged = (ws_size >= WS_NEEDED) ? 1 : 0;

    unsigned long long* keys   = (unsigned long long*)(ws + OFF_KEYS);
    unsigned* hist             = (unsigned*)(ws + OFF_HIST);
    unsigned* cursor           = (unsigned*)(ws + OFF_CUR);
    unsigned* bcnt             = (unsigned*)(ws + OFF_BCNT);
    unsigned* oflow            = (unsigned*)(ws + OFF_OFLW);
    int* meta                  = (int*)(ws + OFF_META);
    unsigned* suf              = (unsigned*)(ws + OFF_SUF);
    unsigned long long* bucket = (unsigned long long*)(ws + OFF_BUCK);

    // zero hist+cursor+bcnt+oflow+meta (contiguous), and output
    hipMemsetAsync(ws + OFF_HIST, 0, SZ_HIST + SZ_CUR + SZ_BCNT + SZ_OFLW + SZ_META, stream);
    hipMemsetAsync(d_out, 0, (size_t)out_size * sizeof(float), stream);

    k_stage<<<dim3(BATCH * SBLK), dim3(256), 0, stream>>>(pred, hist, bcnt, bucket, oflow, staged);
    k_scan<<<dim3(BATCH), dim3(256), 0, stream>>>(hist, suf, meta, oflow, staged);
    k_scatter_fb<<<dim3(BATCH * SBLK), dim3(256), 0, stream>>>(pred, suf, meta, cursor, keys);
    k_nms<<<dim3(BATCH), dim3(512), 0, stream>>>(pred, suf, meta, keys, bucket, outp);
}

// Round 4
// 360.419 us; speedup vs baseline: 1.6501x; 1.1614x over previous
//
#include <hip/hip_runtime.h>
#include <stdint.h>

#define BATCH 16
#define NROW 25200
#define NCLS 80
#define ROWF 85
#define MAXDET 300
#define MAXNMS 30000u
#define NBIN 3072
#define BASEBITS 0x3EC00000u
#define CAP 32768u
#define BATCH_FLOATS 2142000   // 25200*85

#define PREBIN 2048            // score >= 0.75
#define NBUCK 1024             // NBIN - PREBIN
#define BUCKCAP 256

#define GATHER_MIN 512u
#define SORTCAP 1024
#define CH_SZ 128

// fallback-hist tiling (R3-proven structure)
#define TILE_ROWS 80
#define TILE_FLOATS 6800
#define RPB 400
#define SUBT 5
#define SBLK 63

// staging grid
#define ROWS_PER_BLK 256
#define SBLK2 99               // ceil(25200/256)

// exact: fl(inter/den) > 0.5, division only at the rounding boundary
__device__ __forceinline__ bool iou_gt_half(float ax1, float ay1, float ax2, float ay2, float aa,
                                            float bx1, float by1, float bx2, float by2, float ba) {
    float ltx = fmaxf(ax1, bx1), lty = fmaxf(ay1, by1);
    float rbx = fminf(ax2, bx2), rby = fminf(ay2, by2);
    float wx = fmaxf(__fsub_rn(rbx, ltx), 0.0f);
    float wy = fmaxf(__fsub_rn(rby, lty), 0.0f);
    float inter = __fmul_rn(wx, wy);
    float den = __fadd_rn(__fsub_rn(__fadd_rn(aa, ba), inter), 1e-9f);
    float t = __fmul_rn(0.5f, den);            // exact (pow2 scale, den >= 1e-9)
    if (!(inter > t)) return false;            // r <= 0.5  ->  fl(r) <= 0.5
    float tg = __fmul_rn(0.50000012f, den);    // safely above the tie zone
    if (inter >= tg) return true;
    return __fdiv_rn(inter, den) > 0.5f;       // boundary: exact division
}

// ---------------- K1: threshold-only bucket staging (single read, no histogram) ------
__global__ __launch_bounds__(256) void k_stage(const float* __restrict__ pred,
                                               unsigned* __restrict__ bcnt,
                                               unsigned long long* __restrict__ bucket,
                                               unsigned* __restrict__ oflow,
                                               int staged) {
    if (!staged) return;
    int bx = blockIdx.x;
    int b = bx / SBLK2, blk = bx - b * SBLK2;
    int t = threadIdx.x, lane = t & 63, wv = t >> 6;
    const float* pb = pred + (size_t)b * BATCH_FLOATS;
    unsigned* bc = bcnt + (size_t)b * NBUCK;
    unsigned long long* bk = bucket + (size_t)b * NBUCK * BUCKCAP;
    int r0 = blk * ROWS_PER_BLK + wv * 64;
    int rown = NROW - r0;
    if (rown <= 0) return;
    if (rown > 64) rown = 64;
    float obj = 0.0f;
    if (lane < rown) obj = pb[(size_t)(r0 + lane) * ROWF + 4];
    unsigned long long live = __ballot(obj > 0.4f);
    while (live) {
        int j = (int)__builtin_ctzll(live);
        live &= live - 1ULL;
        float o = __shfl(obj, j);
        const float* rp = pb + (size_t)(r0 + j) * ROWF;
        unsigned grow = (unsigned)(r0 + j);
        // half 1: classes 0..63
        {
            float cv = rp[5 + lane];
            float s = __fmul_rn(cv, o);
            if (s >= 0.75f) {
                unsigned bits = __float_as_uint(s);
                unsigned bin = (bits - BASEBITS) >> 12;
                if (bin > (unsigned)(NBIN - 1)) bin = NBIN - 1;
                unsigned bb = bin - PREBIN;
                unsigned pos = atomicAdd(&bc[bb], 1u);
                if (pos < (unsigned)BUCKCAP) {
                    unsigned flat = grow * (unsigned)NCLS + (unsigned)lane;
                    bk[(size_t)bb * BUCKCAP + pos] =
                        ((unsigned long long)bits << 32) |
                        (unsigned long long)(0xFFFFFFFFu - flat);
                } else oflow[b] = 1u;
            }
        }
        // half 2: classes 64..79
        if (lane < 16) {
            int c = 64 + lane;
            float cv = rp[5 + c];
            float s = __fmul_rn(cv, o);
            if (s >= 0.75f) {
                unsigned bits = __float_as_uint(s);
                unsigned bin = (bits - BASEBITS) >> 12;
                if (bin > (unsigned)(NBIN - 1)) bin = NBIN - 1;
                unsigned bb = bin - PREBIN;
                unsigned pos = atomicAdd(&bc[bb], 1u);
                if (pos < (unsigned)BUCKCAP) {
                    unsigned flat = grow * (unsigned)NCLS + (unsigned)c;
                    bk[(size_t)bb * BUCKCAP + pos] =
                        ((unsigned long long)bits << 32) |
                        (unsigned long long)(0xFFFFFFFFu - flat);
                } else oflow[b] = 1u;
            }
        }
    }
}

// ---------------- K2: scan bcnt -> cutoff/need/total/valid + suf2 --------------------
__global__ __launch_bounds__(256) void k_prep(const unsigned* __restrict__ bcnt,
                                              const unsigned* __restrict__ oflow,
                                              unsigned* __restrict__ suf2,
                                              int* __restrict__ meta,
                                              int staged) {
    __shared__ unsigned sh[NBUCK];
    __shared__ unsigned sS[NBUCK];
    __shared__ unsigned cs[256];
    __shared__ int s_cut, s_need, s_tot;
    int b = blockIdx.x, t = threadIdx.x;
    const unsigned* bc = bcnt + (size_t)b * NBUCK;
    for (int i = t; i < NBUCK; i += 256) sh[i] = bc[i];
    if (t == 0) { s_cut = -1; s_need = 0; s_tot = 0; }
    __syncthreads();
    const int CHUNK = NBUCK / 256;  // 4
    int base = t * CHUNK;
    unsigned tot = 0;
    for (int i = 0; i < CHUNK; ++i) tot += sh[base + i];
    cs[t] = tot;
    __syncthreads();
    for (int off = 1; off < 256; off <<= 1) {
        unsigned v = (t + off < 256) ? cs[t + off] : 0u;
        __syncthreads();
        cs[t] += v;
        __syncthreads();
    }
    unsigned after = (t + 1 < 256) ? cs[t + 1] : 0u;
    for (int i = CHUNK - 1; i >= 0; --i) {
        after += sh[base + i];
        sS[base + i] = after;
    }
    __syncthreads();
    unsigned* g2 = suf2 + (size_t)b * (NBUCK + 1);
    for (int i = t; i < NBUCK; i += 256) g2[i] = sS[i];
    if (t == 0) g2[NBUCK] = 0u;
    for (int i = 0; i < CHUNK; ++i) {
        int v = base + i;
        unsigned Sv = sS[v];
        unsigned Sn = (v + 1 < NBUCK) ? sS[v + 1] : 0u;
        if (Sv >= MAXNMS && Sn < MAXNMS) {
            s_cut = PREBIN + v;
            s_need = (int)(MAXNMS - Sn);
            s_tot = (int)Sv;
        }
    }
    __syncthreads();
    if (t == 0) {
        int valid = (staged && s_cut >= 0 && sS[0] >= MAXNMS && oflow[b] == 0u) ? 1 : 0;
        meta[b * 4 + 0] = valid ? s_cut : 0;
        meta[b * 4 + 1] = valid ? s_need : 0;
        meta[b * 4 + 2] = valid ? s_tot : 0;
        meta[b * 4 + 3] = valid;
    }
}

// ---------------- K3a (fallback): full histogram (R3-proven tile structure) ----------
__global__ __launch_bounds__(256) void k_hist_fb(const float* __restrict__ pred,
                                                 unsigned* __restrict__ hist,
                                                 const int* __restrict__ meta) {
    int bx = blockIdx.x;
    int b = bx / SBLK, blk = bx - b * SBLK;
    if (meta[b * 4 + 3]) return;
    __shared__ __align__(16) float rows[TILE_FLOATS];
    __shared__ unsigned shist[NBIN];
    int t = threadIdx.x, lane = t & 63, wv = t >> 6;
    for (int i = t; i < NBIN; i += 256) shist[i] = 0u;
    const float* pbase = pred + (size_t)b * BATCH_FLOATS + (size_t)blk * RPB * ROWF;
    for (int st = 0; st < SUBT; ++st) {
        __syncthreads();
        const float4* src = (const float4*)(pbase + (size_t)st * TILE_ROWS * ROWF);
        float4* dst = (float4*)rows;
        for (int i = t; i < TILE_FLOATS / 4; i += 256) dst[i] = src[i];
        __syncthreads();
        for (int r = wv; r < TILE_ROWS; r += 4) {
            float obj = rows[r * ROWF + 4];
            if (!(obj > 0.4f)) continue;
            for (int half = 0; half < 2; ++half) {
                int c = lane + (half << 6);
                if (c < NCLS) {
                    float cv = rows[r * ROWF + 5 + c];
                    float s = __fmul_rn(cv, obj);
                    if (s > 0.4f) {
                        unsigned bits = __float_as_uint(s);
                        unsigned bin = (bits - BASEBITS) >> 12;
                        if (bin > (unsigned)(NBIN - 1)) bin = NBIN - 1;
                        atomicAdd(&shist[bin], 1u);
                    }
                }
            }
        }
    }
    __syncthreads();
    unsigned* gh = hist + (size_t)b * NBIN;
    for (int i = t; i < NBIN; i += 256) {
        unsigned v = shist[i];
        if (v) atomicAdd(&gh[i], v);
    }
}

// ---------------- K3b (fallback): suffix-scan full hist -> meta + suf ----------------
__global__ __launch_bounds__(256) void k_scan_fb(const unsigned* __restrict__ hist,
                                                 unsigned* __restrict__ suf,
                                                 int* __restrict__ meta) {
    int b = blockIdx.x, t = threadIdx.x;
    if (meta[b * 4 + 3]) return;
    __shared__ unsigned sh[NBIN];
    __shared__ unsigned sS[NBIN];
    __shared__ unsigned cs[256];
    __shared__ int s_cut, s_need, s_tot;
    const unsigned* gh = hist + (size_t)b * NBIN;
    for (int i = t; i < NBIN; i += 256) sh[i] = gh[i];
    if (t == 0) { s_cut = 0; s_need = 0x7FFFFFFF; s_tot = 0; }
    __syncthreads();
    const int CHUNK = NBIN / 256;  // 12
    int base = t * CHUNK;
    unsigned tot = 0;
    for (int i = 0; i < CHUNK; ++i) tot += sh[base + i];
    cs[t] = tot;
    __syncthreads();
    for (int off = 1; off < 256; off <<= 1) {
        unsigned v = (t + off < 256) ? cs[t + off] : 0u;
        __syncthreads();
        cs[t] += v;
        __syncthreads();
    }
    unsigned after = (t + 1 < 256) ? cs[t + 1] : 0u;
    for (int i = CHUNK - 1; i >= 0; --i) {
        after += sh[base + i];
        sS[base + i] = after;
    }
    __syncthreads();
    unsigned* gs = suf + (size_t)b * (NBIN + 1);
    for (int i = t; i < NBIN; i += 256) gs[i] = sS[i];
    if (t == 0) gs[NBIN] = 0u;
    for (int i = 0; i < CHUNK; ++i) {
        int v = base + i;
        unsigned Sv = sS[v];
        unsigned Sn = (v + 1 < NBIN) ? sS[v + 1] : 0u;
        if (Sv >= MAXNMS && Sn < MAXNMS) {
            s_cut = v;
            s_need = (int)(MAXNMS - Sn);
            s_tot = (int)Sv;
        }
    }
    __syncthreads();
    if (t == 0) {
        int cut = s_cut, needv = s_need, totv = s_tot;
        if (sS[0] < MAXNMS) { cut = 0; needv = 0x7FFFFFFF; totv = (int)sS[0]; }
        meta[b * 4 + 0] = cut;
        meta[b * 4 + 1] = needv;
        meta[b * 4 + 2] = totv;
        // meta[b*4+3] stays 0 (fallback)
    }
}

// ---------------- K3c (fallback): full re-read counting-scatter ----------------------
__global__ __launch_bounds__(256) void k_scatter_fb(const float* __restrict__ pred,
                                                    const unsigned* __restrict__ suf,
                                                    const int* __restrict__ meta,
                                                    unsigned* __restrict__ cursor,
                                                    unsigned long long* __restrict__ keys) {
    int bx = blockIdx.x;
    int b = bx / SBLK, blk = bx - b * SBLK;
    if (meta[b * 4 + 3]) return;
    __shared__ __align__(16) float rows[TILE_FLOATS];
    int t = threadIdx.x, lane = t & 63, wv = t >> 6;
    int cutbin = meta[b * 4 + 0];
    const float* pbase = pred + (size_t)b * BATCH_FLOATS + (size_t)blk * RPB * ROWF;
    unsigned rowbase0 = (unsigned)(blk * RPB);
    const unsigned* gs = suf + (size_t)b * (NBIN + 1);
    unsigned* cur = cursor + (size_t)b * NBIN;
    unsigned long long* kb = keys + (size_t)b * CAP;
    for (int st = 0; st < SUBT; ++st) {
        __syncthreads();
        const float4* src = (const float4*)(pbase + (size_t)st * TILE_ROWS * ROWF);
        float4* dst = (float4*)rows;
        for (int i = t; i < TILE_FLOATS / 4; i += 256) dst[i] = src[i];
        __syncthreads();
        for (int r = wv; r < TILE_ROWS; r += 4) {
            float obj = rows[r * ROWF + 4];
            if (!(obj > 0.4f)) continue;
            unsigned grow = rowbase0 + (unsigned)(st * TILE_ROWS + r);
            for (int half = 0; half < 2; ++half) {
                int c = lane + (half << 6);
                if (c < NCLS) {
                    float cv = rows[r * ROWF + 5 + c];
                    float s = __fmul_rn(cv, obj);
                    if (s > 0.4f) {
                        unsigned bits = __float_as_uint(s);
                        unsigned bin = (bits - BASEBITS) >> 12;
                        if (bin > (unsigned)(NBIN - 1)) bin = NBIN - 1;
                        if ((int)bin >= cutbin) {
                            unsigned pos = gs[bin + 1] + atomicAdd(&cur[bin], 1u);
                            if (pos < CAP) {
                                unsigned flat = grow * (unsigned)NCLS + (unsigned)c;
                                kb[pos] = ((unsigned long long)bits << 32) |
                                          (unsigned long long)(0xFFFFFFFFu - flat);
                            }
                        }
                    }
                }
            }
        }
    }
}

// ---------------- K4: NMS — rank-place gather, 128-chunk split mask, div-free IoU ----
__global__ __launch_bounds__(1024) void k_nms(const float* __restrict__ pred,
                                              const unsigned* __restrict__ suf,
                                              const unsigned* __restrict__ suf2,
                                              const int* __restrict__ meta,
                                              const unsigned long long* __restrict__ keys,
                                              const unsigned long long* __restrict__ bucket,
                                              float* __restrict__ out) {
    __shared__ unsigned sgsL[NBUCK + 1];                  // 4.1 KB (valid path)
    __shared__ unsigned long long ktmp[SORTCAP];          // 8 KB
    __shared__ unsigned long long skeys[SORTCAP];         // 8 KB
    __shared__ unsigned maskW[CH_SZ][5];                  // 2.5 KB (4 words + pad)
    __shared__ unsigned sup0w[4];
    __shared__ float cbox[CH_SZ][9];                      // 4.6 KB (stride 9: bank-safe)
    __shared__ float kept[MAXDET][5];                     // 6 KB
    __shared__ int klist[MAXDET];
    __shared__ int s_nk, s_localk;

    int b = blockIdx.x;
    int tid = threadIdx.x;
    int lane = tid & 63, wv = tid >> 6;

    int cutbin = meta[b * 4 + 0];
    int needv  = meta[b * 4 + 1];
    unsigned total = (unsigned)meta[b * 4 + 2];
    int valid  = meta[b * 4 + 3];
    if (total > CAP) total = CAP;     // only matters on fallback (kb capped)
    const unsigned* gs = suf + (size_t)b * (NBIN + 1);
    const unsigned* g2 = suf2 + (size_t)b * (NBUCK + 1);
    const unsigned long long* kb = keys + (size_t)b * CAP;
    const unsigned long long* bk = bucket + (size_t)b * NBUCK * BUCKCAP;
    const float* pb = pred + (size_t)b * BATCH_FLOATS;
    float* ob = out + (size_t)b * MAXDET * 6;

    if (valid) for (int i = tid; i < NBUCK + 1; i += 1024) sgsL[i] = g2[i];
    if (tid == 0) s_nk = 0;
    __syncthreads();

    unsigned limit;
    if (needv == 0x7FFFFFFF) limit = total;
    else limit = (valid ? sgsL[cutbin + 1 - PREBIN] : gs[cutbin + 1]) + (unsigned)needv;
    if (limit > total) limit = total;

#define GSV(v) (valid ? sgsL[(v) - PREBIN] : gs[(v)])

    unsigned p = 0;
    while (p < limit) {
        if (s_nk >= MAXDET) break;

        // ---- gather extent: whole bins, >= GATHER_MIN keys, <= SORTCAP ----
        int lo = cutbin, hi = NBIN - 1, w1 = cutbin;
        while (lo <= hi) { int mid = (lo + hi) >> 1;
            if (GSV(mid) > p) { w1 = mid; lo = mid + 1; } else hi = mid - 1; }
        lo = cutbin; hi = NBIN - 1; int w2 = cutbin;
        while (lo <= hi) { int mid = (lo + hi) >> 1;
            if (GSV(mid) >= p + GATHER_MIN) { w2 = mid; lo = mid + 1; } else hi = mid - 1; }
        unsigned gEnd = GSV(w2);
        if (gEnd <= p) gEnd = GSV(cutbin);
        if (gEnd - p > (unsigned)SORTCAP) {
            if (w2 < w1) gEnd = GSV(w2 + 1);
            if (gEnd - p > (unsigned)SORTCAP) gEnd = p + SORTCAP;  // degenerate only
        }
        unsigned G = gEnd - p;

        // ---- rank-place: keys already bin-partitioned; exact order = bin desc, key desc ----
        unsigned myLo = 0, myHi = 0;
        unsigned long long raw = 0ULL;
        if (tid < (int)G) {
            unsigned idx = p + (unsigned)tid;
            int l2 = cutbin, h2 = NBIN - 1, v = cutbin;
            while (l2 <= h2) { int mid = (l2 + h2) >> 1;
                if (GSV(mid) > idx) { v = mid; l2 = mid + 1; } else h2 = mid - 1; }
            unsigned bstart = GSV(v + 1);
            unsigned bend = GSV(v);
            unsigned e = idx - bstart;
            raw = valid ? bk[(size_t)(v - PREBIN) * BUCKCAP + e] : kb[idx];
            myLo = bstart - p;
            myHi = bend - p; if (myHi > G) myHi = G;
            ktmp[tid] = raw;
        }
        __syncthreads();
        if (tid < (int)G) {
            unsigned rank = 0;
            for (unsigned u = myLo; u < myHi; ++u) rank += (ktmp[u] > raw) ? 1u : 0u;
            skeys[myLo + rank] = raw;
        }
        __syncthreads();

        unsigned consumable = limit - p; if (consumable > G) consumable = G;

        // ---- process in chunks of 128 ----
        for (unsigned c0 = 0; c0 < consumable; c0 += CH_SZ) {
            int nk0 = s_nk;
            if (nk0 >= MAXDET) break;
            int CH = (int)((consumable - c0 < (unsigned)CH_SZ) ? (consumable - c0) : (unsigned)CH_SZ);

            // zero mask + sup0
            if (tid < CH_SZ * 5) maskW[tid / 5][tid % 5] = 0u;
            if (tid >= CH_SZ * 5 && tid < CH_SZ * 5 + 4) sup0w[tid - CH_SZ * 5] = 0u;
            // candidate off-boxes (exact fp op order)
            if (tid < CH) {
                unsigned long long kk = skeys[c0 + tid];
                unsigned flat = 0xFFFFFFFFu - (unsigned)kk;
                unsigned bi = flat / (unsigned)NCLS;
                unsigned cc = flat - bi * (unsigned)NCLS;
                const float* rp = pb + (size_t)bi * ROWF;
                float cx = rp[0], cy = rp[1], wd = rp[2], ht = rp[3];
                float hw = __fmul_rn(0.5f, wd), hh = __fmul_rn(0.5f, ht);
                float off = __fmul_rn((float)cc, 4096.0f);
                float x1 = __fsub_rn(cx, hw), y1 = __fsub_rn(cy, hh);
                float x2 = __fadd_rn(cx, hw), y2 = __fadd_rn(cy, hh);
                float ox1 = __fadd_rn(x1, off), oy1 = __fadd_rn(y1, off);
                float ox2 = __fadd_rn(x2, off), oy2 = __fadd_rn(y2, off);
                cbox[tid][0] = ox1; cbox[tid][1] = oy1;
                cbox[tid][2] = ox2; cbox[tid][3] = oy2;
                cbox[tid][4] = __fmul_rn(__fsub_rn(ox2, ox1), __fsub_rn(oy2, oy1));
            }
            __syncthreads();

            // split triangle mask + kept-suppression: thread = (col, part)
            {
                int col = tid & (CH_SZ - 1);
                int part = tid >> 7;               // 0..7, uniform per wave
                if (col < CH) {
                    float bx1 = cbox[col][0], by1 = cbox[col][1];
                    float bx2 = cbox[col][2], by2 = cbox[col][3], ba = cbox[col][4];
                    // triangle rows [part*16, part*16+16)
                    unsigned part16 = 0u;
                    int rbase = part << 4;
                    for (int k = 0; k < 16; ++k) {
                        int i2 = rbase + k;
                        if (i2 >= col || i2 >= CH) break;
                        if (iou_gt_half(cbox[i2][0], cbox[i2][1], cbox[i2][2], cbox[i2][3],
                                        cbox[i2][4], bx1, by1, bx2, by2, ba))
                            part16 |= (1u << k);
                    }
                    if (part16)
                        atomicOr(&maskW[col][part >> 1], part16 << ((part & 1) << 4));
                    // suppression vs already-kept (strided over parts)
                    bool f = false;
                    for (int k2 = part; k2 < nk0; k2 += 8) {
                        if (iou_gt_half(kept[k2][0], kept[k2][1], kept[k2][2], kept[k2][3],
                                        kept[k2][4], bx1, by1, bx2, by2, ba)) f = true;
                    }
                    if (f) atomicOr(&sup0w[col >> 5], 1u << (col & 31));
                }
            }
            __syncthreads();

            // serial greedy scan (wave 0): lanes 0..3 hold kept-bitset words
            if (wv == 0) {
                unsigned keptw = 0u;
                int nkv = nk0, lk = 0;
                unsigned pre0 = (lane < 4 && CH > 0) ? maskW[0][lane] : 0u;
                unsigned pre1 = (lane < 4 && CH > 1) ? maskW[1][lane] : 0u;
                for (int j = 0; j < CH && nkv < MAXDET; ++j) {
                    unsigned colw = pre0;
                    pre0 = pre1;
                    pre1 = (lane < 4 && (j + 2) < CH) ? maskW[j + 2][lane] : 0u;
                    bool hit = (keptw & colw) != 0u;
                    bool sup = __any(hit);
                    if ((sup0w[j >> 5] >> (j & 31)) & 1u) sup = true;
                    if (!sup) {
                        if (lane == (j >> 5)) keptw |= 1u << (j & 31);
                        if (lane == 0) klist[lk] = j;
                        lk++; nkv++;
                    }
                }
                if (lane == 0) { s_localk = lk; s_nk = nkv; }
            }
            __syncthreads();

            // epilogue: record kept boxes + write output rows
            int lk = s_localk;
            for (int t2 = tid; t2 < lk; t2 += 1024) {
                int i = klist[t2];
                int oidx = nk0 + t2;
                kept[oidx][0] = cbox[i][0]; kept[oidx][1] = cbox[i][1];
                kept[oidx][2] = cbox[i][2]; kept[oidx][3] = cbox[i][3];
                kept[oidx][4] = cbox[i][4];
                unsigned long long kk = skeys[c0 + i];
                unsigned bits = (unsigned)(kk >> 32);
                unsigned flat = 0xFFFFFFFFu - (unsigned)kk;
                unsigned bi = flat / (unsigned)NCLS;
                unsigned cc = flat - bi * (unsigned)NCLS;
                const float* rp = pb + (size_t)bi * ROWF;
                float cx = rp[0], cy = rp[1], wd = rp[2], ht = rp[3];
                float hw = __fmul_rn(0.5f, wd), hh = __fmul_rn(0.5f, ht);
                float* orow = ob + (size_t)oidx * 6;
                orow[0] = __fsub_rn(cx, hw);
                orow[1] = __fsub_rn(cy, hh);
                orow[2] = __fadd_rn(cx, hw);
                orow[3] = __fadd_rn(cy, hh);
                orow[4] = __uint_as_float(bits);
                orow[5] = (float)cc;
            }
            __syncthreads();
        }
        p = gEnd;
    }
#undef GSV
}

// ---------------- launch --------------------------------------------------------------
extern "C" void kernel_launch(void* const* d_in, const int* in_sizes, int n_in,
                              void* d_out, int out_size, void* d_ws, size_t ws_size,
                              hipStream_t stream) {
    const float* pred = (const float*)d_in[0];
    float* outp = (float*)d_out;
    char* ws = (char*)d_ws;

    const size_t OFF_KEYS = 0;
    const size_t SZ_KEYS  = (size_t)BATCH * CAP * 8;                 // 4,194,304
    const size_t OFF_HIST = OFF_KEYS + SZ_KEYS;
    const size_t SZ_HIST  = (size_t)BATCH * NBIN * 4;                // 196,608
    const size_t OFF_CUR  = OFF_HIST + SZ_HIST;
    const size_t SZ_CUR   = (size_t)BATCH * NBIN * 4;                // 196,608
    const size_t OFF_BCNT = OFF_CUR + SZ_CUR;
    const size_t SZ_BCNT  = (size_t)BATCH * NBUCK * 4;               // 65,536
    const size_t OFF_OFLW = OFF_BCNT + SZ_BCNT;
    const size_t SZ_OFLW  = (size_t)BATCH * 4;
    const size_t OFF_META = OFF_OFLW + SZ_OFLW;
    const size_t SZ_META  = (size_t)BATCH * 4 * 4;
    const size_t OFF_SUF  = OFF_META + SZ_META;
    const size_t SZ_SUF   = (size_t)BATCH * (NBIN + 1) * 4;          // 196,672
    const size_t OFF_SUF2 = OFF_SUF + SZ_SUF;
    const size_t SZ_SUF2  = (size_t)BATCH * (NBUCK + 1) * 4;         // 65,600
    const size_t OFF_BUCK = OFF_SUF2 + SZ_SUF2;
    const size_t SZ_BUCK  = (size_t)BATCH * NBUCK * BUCKCAP * 8;     // 33,554,432
    const size_t WS_NEEDED = OFF_BUCK + SZ_BUCK;

    int staged = (ws_size >= WS_NEEDED) ? 1 : 0;

    unsigned long long* keys   = (unsigned long long*)(ws + OFF_KEYS);
    unsigned* hist             = (unsigned*)(ws + OFF_HIST);
    unsigned* cursor           = (unsigned*)(ws + OFF_CUR);
    unsigned* bcnt             = (unsigned*)(ws + OFF_BCNT);
    unsigned* oflow            = (unsigned*)(ws + OFF_OFLW);
    int* meta                  = (int*)(ws + OFF_META);
    unsigned* suf              = (unsigned*)(ws + OFF_SUF);
    unsigned* suf2             = (unsigned*)(ws + OFF_SUF2);
    unsigned long long* bucket = (unsigned long long*)(ws + OFF_BUCK);

    // zero hist+cursor+bcnt+oflow+meta (contiguous), and output
    hipMemsetAsync(ws + OFF_HIST, 0, SZ_HIST + SZ_CUR + SZ_BCNT + SZ_OFLW + SZ_META, stream);
    hipMemsetAsync(d_out, 0, (size_t)out_size * sizeof(float), stream);

    k_stage<<<dim3(BATCH * SBLK2), dim3(256), 0, stream>>>(pred, bcnt, bucket, oflow, staged);
    k_prep<<<dim3(BATCH), dim3(256), 0, stream>>>(bcnt, oflow, suf2, meta, staged);
    k_hist_fb<<<dim3(BATCH * SBLK), dim3(256), 0, stream>>>(pred, hist, meta);
    k_scan_fb<<<dim3(BATCH), dim3(256), 0, stream>>>(hist, suf, meta);
    k_scatter_fb<<<dim3(BATCH * SBLK), dim3(256), 0, stream>>>(pred, suf, meta, cursor, keys);
    k_nms<<<dim3(BATCH), dim3(1024), 0, stream>>>(pred, suf, suf2, meta, keys, bucket, outp);
}